// Round 9
// baseline (367.254 us; speedup 1.0000x reference)
//
#include <hip/hip_runtime.h>

// HGCN on MI355X. logmap0(expmap0(v)) == v here, so the model reduces to:
//   t1 = sigmoid(segmean(feat@W1+b1)); t2 = sigmoid(segmean(t1@W2+b2))
//   out = relu(t2@W3+b3)@W4 + b4     (segmean commutes with the linear map;
//   deg-0 nodes: segmean = 0 -> value 0.5 exactly, handled via dz check)
// R1-R13: see session journal. R14: re-anchor 229.4us.
// R15: FAILED. LDS float atomicAdd = CAS loop. R16: FAILED. write-amp.
// R17: WIN (219). csr_fine@1024; gathers 128thr/32-row (48us, proven).
// R18: part_prep@512 kept; deeper single chain lost. R19: NULL (not
//   concurrency-bound). R20: NULL (chunk sort; fabric wall ~2TB/s).
// R21: WIN-ish (211.7). CSHIFT 8, but prep block still ~115us total.
// R22: radix machinery DELETED. CSR via direct two-pass global atomics:
//   3.2M int atomics over 100K counters (16/ctr, low contention; R1's wall
//   was 102M fp32 PAYLOAD atomics - different regime). deg pass fused with
//   cast/img; 2-kernel scan (98x1024 shuffle + bsum rescan); scatter claims
//   positions via atomicAdd(cur[d]). ssrc lines fill contiguously ->
//   write-back L2 absorbs. Gathers/GEMMs bit-for-bit unchanged.
//   Pre-commit: scatter>20us => atomic wall real, revert. Predicted
//   211.7 -> ~155-175; aggep3 unchanged 48/79MB.

constexpr int SCAN_B = 1024;            // scan block size

// frag-packed bf16 weight image (shorts). Fragment = 16 lanes x 8 shorts =
// 128 shorts; flat idx = (((c*KK + kk)*4 + quad)*16 + m)*8 + j.
constexpr int W1F_OFF = 0;              // 4x2x4 frags  = 4096 shorts
constexpr int W2F_OFF = 4096;           // 4096
constexpr int W3F_OFF = 8192;           // 8x2x4 frags  = 8192
constexpr int W4F_OFF = 16384;          // 3x4x4 frags  = 6144 (cols padded 48)
constexpr int WIMG_TOT = 22528;

typedef __attribute__((ext_vector_type(8))) short short8;   // 8 bf16
typedef __attribute__((ext_vector_type(4))) float floatx4;  // MFMA acc

__device__ __forceinline__ float sigmoidf(float x) {
    return 1.0f / (1.0f + __expf(-x));
}
__device__ __forceinline__ unsigned short f2bf(float f) {   // RNE f32->bf16
    unsigned int u = __float_as_uint(f);
    u = (u + 0x7FFFu + ((u >> 16) & 1u)) >> 16;
    return (unsigned short)u;
}

// ---------------- degree count + one-time prep (merged launch) -------------
// Blocks [0,gA): deg[dst]++ for 2048 edges each (8-deep batched).
// Blocks [gA,..): feat fp32->bf16 cast + frag-packed weight image build.
__global__ __launch_bounds__(256) void prep_deg_k(
    const int* __restrict__ dst, int* __restrict__ deg, int E, int gA,
    const float* __restrict__ feat, unsigned short* __restrict__ featbf,
    const float* __restrict__ W1, const float* __restrict__ W2,
    const float* __restrict__ W3, const float* __restrict__ W4,
    unsigned short* __restrict__ img, int n8)
{
    const int tid = threadIdx.x;

    if ((int)blockIdx.x < gA) {
        // ---- degree path ----
        const int base = blockIdx.x * 2048;
        int dv[8];
        #pragma unroll
        for (int k = 0; k < 8; k++) {
            int id = base + tid + k * 256;
            dv[k] = (id < E) ? dst[id] : -1;
        }
        #pragma unroll
        for (int k = 0; k < 8; k++)
            if (dv[k] >= 0) atomicAdd(&deg[dv[k]], 1);
        return;
    }

    // ---- prep path ----
    int i = ((int)blockIdx.x - gA) * 256 + tid;
    if (i < n8) {
        const float4* p = (const float4*)feat + (size_t)i * 2;
        float4 a = p[0], b = p[1];
        uint4 o;
        o.x = (unsigned)f2bf(a.x) | ((unsigned)f2bf(a.y) << 16);
        o.y = (unsigned)f2bf(a.z) | ((unsigned)f2bf(a.w) << 16);
        o.z = (unsigned)f2bf(b.x) | ((unsigned)f2bf(b.y) << 16);
        o.w = (unsigned)f2bf(b.z) | ((unsigned)f2bf(b.w) << 16);
        ((uint4*)featbf)[i] = o;
        return;
    }
    int t = i - n8;
    if (t >= WIMG_TOT) return;
    float v = 0.f;
    int s = t;
    if (s < W2F_OFF) {                       // W1 [64x64]
        int j = s & 7, m = (s >> 3) & 15, q = (s >> 7) & 3, kk = (s >> 9) & 1, c = s >> 10;
        v = W1[(kk * 32 + q * 8 + j) * 64 + c * 16 + m];
    } else if (s < W3F_OFF) {                // W2 [64x64]
        s -= W2F_OFF;
        int j = s & 7, m = (s >> 3) & 15, q = (s >> 7) & 3, kk = (s >> 9) & 1, c = s >> 10;
        v = W2[(kk * 32 + q * 8 + j) * 64 + c * 16 + m];
    } else if (s < W4F_OFF) {                // W3 [64x128]
        s -= W3F_OFF;
        int j = s & 7, m = (s >> 3) & 15, q = (s >> 7) & 3, kk = (s >> 9) & 1, c = s >> 10;
        v = W3[(kk * 32 + q * 8 + j) * 128 + c * 16 + m];
    } else {                                 // W4 [128x40], cols padded 48
        s -= W4F_OFF;
        int j = s & 7, m = (s >> 3) & 15, q = (s >> 7) & 3, kk = (s >> 9) & 3, c = s >> 11;
        int n = c * 16 + m;
        if (n < 40) v = W4[(kk * 32 + q * 8 + j) * 40 + n];
    }
    img[t] = f2bf(v);
}

// ---------------- scan phase 1: block-local prefix of deg ------------------
__global__ __launch_bounds__(SCAN_B) void scan1_k(
    const int* __restrict__ deg, int* __restrict__ off,
    int* __restrict__ bsum, int N)
{
    __shared__ int wsum[16];
    __shared__ int wpre[16];
    const int tid = threadIdx.x;
    const int lane = tid & 63, wid = tid >> 6;
    const int i = blockIdx.x * SCAN_B + tid;

    int d = (i < N) ? deg[i] : 0;
    int v = d;
    #pragma unroll
    for (int k = 1; k < 64; k <<= 1) {
        int t = __shfl_up(v, k);
        if (lane >= k) v += t;
    }
    if (lane == 63) wsum[wid] = v;
    __syncthreads();
    if (tid == 0) {
        int s = 0;
        #pragma unroll
        for (int k = 0; k < 16; k++) { int t = wsum[k]; wpre[k] = s; s += t; }
        bsum[blockIdx.x] = s;
    }
    __syncthreads();
    if (i < N) off[i] = wpre[wid] + v - d;   // block-local exclusive prefix
}

// ---------------- scan phase 2: add block offsets, init cur ----------------
__global__ __launch_bounds__(SCAN_B) void scan2_k(
    const int* __restrict__ bsum, int* __restrict__ off,
    int* __restrict__ cur, int N, int E)
{
    __shared__ int bpre_s;
    const int tid = threadIdx.x;
    if (tid == 0) {
        int s = 0;
        for (int k = 0; k < (int)blockIdx.x; k++) s += bsum[k];  // L2-hot
        bpre_s = s;
    }
    __syncthreads();
    const int i = blockIdx.x * SCAN_B + tid;
    if (i < N) {
        int o = off[i] + bpre_s;
        off[i] = o;
        cur[i] = o;
    }
    if (blockIdx.x == 0 && tid == 0) off[N] = E;
}

// ---------------- scatter: claim position, write src -----------------------
__global__ __launch_bounds__(256) void scatter_k(
    const int* __restrict__ src, const int* __restrict__ dst,
    int* __restrict__ cur, int* __restrict__ ssrc, int E)
{
    const int tid = threadIdx.x;
    const int base = blockIdx.x * 2048;
    int sv[8], dv[8];
    #pragma unroll
    for (int k = 0; k < 8; k++) {
        int id = base + tid + k * 256;
        if (id < E) { sv[k] = src[id]; dv[k] = dst[id]; }
        else dv[k] = -1;
    }
    int pos[8];
    #pragma unroll
    for (int k = 0; k < 8; k++)
        if (dv[k] >= 0) pos[k] = atomicAdd(&cur[dv[k]], 1);
    #pragma unroll
    for (int k = 0; k < 8; k++)
        if (dv[k] >= 0) ssrc[pos[k]] = sv[k];
}

// ---------------- wave-local gather: mean of h[src] rows into LDS tile -----
// Wave w gathers ITS OWN rows w*16..w*16+15 (2 passes x 8 rows x 8 lanes).
// (R17/R21 proven config: 8-deep batched loads. UNCHANGED.)
#define ACC8(v)                                    \
    acc[0] += __uint_as_float((v).x << 16);        \
    acc[1] += __uint_as_float((v).x & 0xFFFF0000u);\
    acc[2] += __uint_as_float((v).y << 16);        \
    acc[3] += __uint_as_float((v).y & 0xFFFF0000u);\
    acc[4] += __uint_as_float((v).z << 16);        \
    acc[5] += __uint_as_float((v).z & 0xFFFF0000u);\
    acc[6] += __uint_as_float((v).w << 16);        \
    acc[7] += __uint_as_float((v).w & 0xFFFF0000u);

__device__ __forceinline__ void gather_tile_wave(
    const unsigned short* __restrict__ h, const int* __restrict__ off,
    const int* __restrict__ ssrc, unsigned short* Agg, int rowB, int N,
    int w, int lane)
{
    #pragma unroll
    for (int pass = 0; pass < 2; pass++) {
        int rl = w * 16 + pass * 8 + (lane >> 3);
        int g  = rowB + rl;
        int q  = (lane & 7) * 8;
        uint4 p = make_uint4(0u, 0u, 0u, 0u);
        if (g < N) {
            int beg = off[g], end = off[g + 1];
            float acc[8] = {0.f, 0.f, 0.f, 0.f, 0.f, 0.f, 0.f, 0.f};
            int i = beg;
            for (; i + 8 <= end; i += 8) {       // 8 loads in flight per lane
                uint4 v0 = *(const uint4*)(h + (size_t)ssrc[i]     * 64 + q);
                uint4 v1 = *(const uint4*)(h + (size_t)ssrc[i + 1] * 64 + q);
                uint4 v2 = *(const uint4*)(h + (size_t)ssrc[i + 2] * 64 + q);
                uint4 v3 = *(const uint4*)(h + (size_t)ssrc[i + 3] * 64 + q);
                uint4 v4 = *(const uint4*)(h + (size_t)ssrc[i + 4] * 64 + q);
                uint4 v5 = *(const uint4*)(h + (size_t)ssrc[i + 5] * 64 + q);
                uint4 v6 = *(const uint4*)(h + (size_t)ssrc[i + 6] * 64 + q);
                uint4 v7 = *(const uint4*)(h + (size_t)ssrc[i + 7] * 64 + q);
                ACC8(v0); ACC8(v1); ACC8(v2); ACC8(v3);
                ACC8(v4); ACC8(v5); ACC8(v6); ACC8(v7);
            }
            for (; i + 2 <= end; i += 2) {
                uint4 v0 = *(const uint4*)(h + (size_t)ssrc[i]     * 64 + q);
                uint4 v1 = *(const uint4*)(h + (size_t)ssrc[i + 1] * 64 + q);
                ACC8(v0); ACC8(v1);
            }
            for (; i < end; i++) {
                uint4 v = *(const uint4*)(h + (size_t)ssrc[i] * 64 + q);
                ACC8(v);
            }
            // v_rcp_f32: 2^-22 rel err, absorbed by the bf16 round
            float inv = __builtin_amdgcn_rcpf((float)max(end - beg, 1));
            p.x = (unsigned)f2bf(acc[0]*inv) | ((unsigned)f2bf(acc[1]*inv) << 16);
            p.y = (unsigned)f2bf(acc[2]*inv) | ((unsigned)f2bf(acc[3]*inv) << 16);
            p.z = (unsigned)f2bf(acc[4]*inv) | ((unsigned)f2bf(acc[5]*inv) << 16);
            p.w = (unsigned)f2bf(acc[6]*inv) | ((unsigned)f2bf(acc[7]*inv) << 16);
        }
        *(uint4*)(Agg + rl * 72 + q) = p;
    }
}

// ---------------- fused gather + GEMM1 + sigmoid -> t1 ---------------------
// 128 threads / 32-row tile, grid 3125 (R17 best config, unchanged).
__global__ __launch_bounds__(128) void aggemm1_k(
    const unsigned short* __restrict__ featbf, const int* __restrict__ off,
    const int* __restrict__ ssrc, const unsigned short* __restrict__ img,
    const float* __restrict__ bias, unsigned short* __restrict__ t1, int N)
{
    __shared__ alignas(16) unsigned short Agg[32 * 72];   // 4.6 KB

    const int tid = threadIdx.x;
    const int rowB = blockIdx.x * 32;
    const int w = tid >> 6, lane = tid & 63;
    const int m = lane & 15, quad = lane >> 4;
    const int row0 = rowB + w * 16;

    gather_tile_wave(featbf, off, ssrc, Agg, rowB, N, w, lane);

    const short8* Wf = (const short8*)(img + W1F_OFF);
    floatx4 acc[4];
    #pragma unroll
    for (int c = 0; c < 4; c++) acc[c] = (floatx4){0.f, 0.f, 0.f, 0.f};
    #pragma unroll
    for (int kk = 0; kk < 2; kk++) {
        short8 a = *(const short8*)(Agg + (w * 16 + m) * 72 + kk * 32 + quad * 8);
        #pragma unroll
        for (int c = 0; c < 4; c++) {
            short8 b = Wf[((c * 2 + kk) * 4 + quad) * 16 + m];
            acc[c] = __builtin_amdgcn_mfma_f32_16x16x32_bf16(a, b, acc[c], 0, 0, 0);
        }
    }
    bool dzr[4];
    int rows[4];
    #pragma unroll
    for (int r = 0; r < 4; r++) {
        rows[r] = row0 + quad * 4 + r;
        dzr[r] = (rows[r] < N) ? (off[rows[r] + 1] == off[rows[r]]) : false;
    }
    #pragma unroll
    for (int c = 0; c < 4; c++) {
        int col = c * 16 + m;
        float bv = bias[col];
        #pragma unroll
        for (int r = 0; r < 4; r++) {
            if (rows[r] < N) {
                float v = dzr[r] ? 0.5f : sigmoidf(acc[c][r] + bv);
                t1[(size_t)rows[r] * 64 + col] = f2bf(v);
            }
        }
    }
}

// ---------------- fused gather + triple-GEMM -> out ------------------------
// 128 threads / 32-row tile; LDS: T2[0,2304) | Agg/H3h[2304,4608) shorts.
// Every LDS row is touched only by its owning wave -> no __syncthreads.
__global__ __launch_bounds__(128) void aggep3_k(
    const unsigned short* __restrict__ t1, const int* __restrict__ off,
    const int* __restrict__ ssrc, const unsigned short* __restrict__ img,
    const float* __restrict__ b2, const float* __restrict__ b3,
    const float* __restrict__ b4, float* __restrict__ out, int N)
{
    __shared__ alignas(16) unsigned short SM[4608];   // 9.2 KB
    unsigned short* T2  = SM;            // 32 x 72
    unsigned short* Agg = SM + 2304;     // 32 x 72 (dead after phase 0)
    unsigned short* H3h = SM + 2304;     // aliases Agg

    const int tid = threadIdx.x;
    const int rowB = blockIdx.x * 32;
    const int w = tid >> 6, lane = tid & 63;
    const int m = lane & 15, quad = lane >> 4;
    const int row0 = rowB + w * 16;

    gather_tile_wave(t1, off, ssrc, Agg, rowB, N, w, lane);

    // ---- phase 0: T2 = sigmoid(Agg @ W2 + b2) ----
    {
        const short8* Wf = (const short8*)(img + W2F_OFF);
        floatx4 acc[4];
        #pragma unroll
        for (int c = 0; c < 4; c++) acc[c] = (floatx4){0.f, 0.f, 0.f, 0.f};
        #pragma unroll
        for (int kk = 0; kk < 2; kk++) {
            short8 a = *(const short8*)(Agg + (w * 16 + m) * 72 + kk * 32 + quad * 8);
            #pragma unroll
            for (int c = 0; c < 4; c++) {
                short8 b = Wf[((c * 2 + kk) * 4 + quad) * 16 + m];
                acc[c] = __builtin_amdgcn_mfma_f32_16x16x32_bf16(a, b, acc[c], 0, 0, 0);
            }
        }
        bool dzr[4];
        #pragma unroll
        for (int r = 0; r < 4; r++) {
            int row = row0 + quad * 4 + r;
            dzr[r] = (row < N) ? (off[row + 1] == off[row]) : false;
        }
        #pragma unroll
        for (int c = 0; c < 4; c++) {
            int col = c * 16 + m;
            float bv = b2[col];
            #pragma unroll
            for (int r = 0; r < 4; r++) {
                int rl = w * 16 + quad * 4 + r;
                float v = dzr[r] ? 0.5f : sigmoidf(acc[c][r] + bv);
                T2[rl * 72 + col] = f2bf(v);
            }
        }
    }

    // ---- phases 1&2 split-K: per half, H3h = relu(T2@W3half+b3half),
    //      then acc2 += H3h @ W4[khalf] ----
    floatx4 acc2[3];
    #pragma unroll
    for (int c = 0; c < 3; c++) acc2[c] = (floatx4){0.f, 0.f, 0.f, 0.f};
    const short8* Wf3 = (const short8*)(img + W3F_OFF);
    const short8* Wf4 = (const short8*)(img + W4F_OFF);

    #pragma unroll
    for (int half = 0; half < 2; half++) {
        floatx4 acc[4];
        #pragma unroll
        for (int c = 0; c < 4; c++) acc[c] = (floatx4){0.f, 0.f, 0.f, 0.f};
        #pragma unroll
        for (int kk = 0; kk < 2; kk++) {
            short8 a = *(const short8*)(T2 + (w * 16 + m) * 72 + kk * 32 + quad * 8);
            #pragma unroll
            for (int c = 0; c < 4; c++) {
                short8 b = Wf3[(((half * 4 + c) * 2 + kk) * 4 + quad) * 16 + m];
                acc[c] = __builtin_amdgcn_mfma_f32_16x16x32_bf16(a, b, acc[c], 0, 0, 0);
            }
        }
        #pragma unroll
        for (int c = 0; c < 4; c++) {
            int col = c * 16 + m;
            float bv = b3[half * 64 + col];
            #pragma unroll
            for (int r = 0; r < 4; r++) {
                int rl = w * 16 + quad * 4 + r;
                H3h[rl * 72 + col] = f2bf(fmaxf(acc[c][r] + bv, 0.f));
            }
        }
        #pragma unroll
        for (int kk2 = 0; kk2 < 2; kk2++) {
            short8 a = *(const short8*)(H3h + (w * 16 + m) * 72 + kk2 * 32 + quad * 8);
            #pragma unroll
            for (int c = 0; c < 3; c++) {
                short8 b = Wf4[((c * 4 + half * 2 + kk2) * 4 + quad) * 16 + m];
                acc2[c] = __builtin_amdgcn_mfma_f32_16x16x32_bf16(a, b, acc2[c], 0, 0, 0);
            }
        }
    }

    // ---- store out = acc2 + b4 ----
    #pragma unroll
    for (int c = 0; c < 3; c++) {
        int col = c * 16 + m;
        if (col < 40) {
            float bv = b4[col];
            #pragma unroll
            for (int r = 0; r < 4; r++) {
                int row = row0 + quad * 4 + r;
                if (row < N) out[(size_t)row * 40 + col] = acc2[c][r] + bv;
            }
        }
    }
}

extern "C" void kernel_launch(void* const* d_in, const int* in_sizes, int n_in,
                              void* d_out, int out_size, void* d_ws, size_t ws_size,
                              hipStream_t stream)
{
    const float* feat = (const float*)d_in[0];
    const int*   eidx = (const int*)d_in[1];
    const float* W1 = (const float*)d_in[2];
    const float* b1 = (const float*)d_in[3];
    const float* W2 = (const float*)d_in[4];
    const float* b2 = (const float*)d_in[5];
    const float* W3 = (const float*)d_in[6];
    const float* b3 = (const float*)d_in[7];
    const float* W4 = (const float*)d_in[8];
    const float* b4 = (const float*)d_in[9];

    const int N = in_sizes[0] / 64;
    const int E = in_sizes[1] / 2;
    const int* src = eidx;
    const int* dst = eidx + E;

    unsigned short* featbf = (unsigned short*)d_ws;            // N*64 bf16
    unsigned short* t1     = featbf + (size_t)N * 64;          // N*64 bf16
    unsigned short* img    = t1     + (size_t)N * 64;          // WIMG_TOT
    int*   off   = (int*)(img + WIMG_TOT);                     // N+1
    int*   cur   = off + (N + 1);                              // N (deg, then cur)
    int*   bsum  = cur + N;                                    // <=128
    int*   ssrc  = bsum + 128;                                 // E
    float* out   = (float*)d_out;

    const int gA  = (E + 2047) / 2048;             // 782 degree blocks
    const int n8  = N * 64 / 8;
    const int gPC = (n8 + WIMG_TOT + 255) / 256;
    const int gS  = (N + SCAN_B - 1) / SCAN_B;     // 98 scan blocks
    const int g32 = (N + 31) / 32;

    // deg=0; deg count + cast + img (merged); 2-phase scan; scatter
    hipMemsetAsync(cur, 0, (size_t)N * sizeof(int), stream);
    prep_deg_k<<<gA + gPC, dim3(256), 0, stream>>>(dst, cur, E, gA, feat,
                                                   featbf, W1, W2, W3, W4,
                                                   img, n8);
    scan1_k<<<gS, dim3(SCAN_B), 0, stream>>>(cur, off, bsum, N);
    scan2_k<<<gS, dim3(SCAN_B), 0, stream>>>(bsum, off, cur, N, E);
    scatter_k<<<gA, dim3(256), 0, stream>>>(src, dst, cur, ssrc, E);

    // t1 = sigmoid(mean(featbf[src]) @ W1 + b1)   [fused, 0 barriers]
    aggemm1_k<<<g32, dim3(128), 0, stream>>>(featbf, off, ssrc, img, b1, t1, N);
    // out = relu(sigmoid(mean(t1[src])@W2+b2)@W3+b3)@W4 + b4  [fused, 0 barriers]
    aggep3_k<<<g32, dim3(128), 0, stream>>>(t1, off, ssrc, img, b2, b3, b4, out, N);
}